// Round 4
// baseline (335.101 us; speedup 1.0000x reference)
//
#include <hip/hip_runtime.h>
#include <hip/hip_bf16.h>

// Problem: B=64, S=512, D=512.
// out[b] = (sum_{valid i} max_{valid j} sim[i,j] + sum_{valid j} max_{valid i} sim[i,j]) / (n1+n2)
// sim = normalize(e1) @ normalize(e2)^T per batch.
//
// Round-11: round-2 structure (75us @ 4 blocks/CU) + the XCD-batch-affinity
// swizzle proven in r10 (FETCH 197->66MB first-run, ~1MB steady), WITHOUT
// r10's regressions:
//   * CVTWRITE back BEFORE the MFMA cluster (r10 moved it after -> staging
//     regs live across 16 MFMAs -> VGPR 124->132 -> crossed the 128 cliff ->
//     blocks/CU 4->2 -> 75->105us. Occupancy is the dominant latency-hiding
//     mechanism here; protect it.)
//   * no setprio (confounded in r10; removed for clean attribution)
//   * __launch_bounds__(256, 4): pin >=4 waves/EU (= 4 blocks/CU for 256-thr
//     blocks) so the allocator can never cross 128 VGPR again.
//   * lgkmcnt(0)-only barriers + 2-deep reg staging kept from r8/r9 (+4%).
// Steady-state regime (r10 counters): input fully L2/L3-resident, HBM ~0.
// ws: 1 MB (partial maxes only).

typedef __attribute__((ext_vector_type(8))) short bf16x8;   // 8 bf16 in 4 VGPRs
typedef __attribute__((ext_vector_type(4))) float f32x4;

#define NEGBIG (-1e9f)

__device__ __forceinline__ unsigned packbf2_hw(float lo, float hi) {
    __hip_bfloat162 h = __float22bfloat162_rn(float2{lo, hi});
    union { __hip_bfloat162 h; unsigned u; } c; c.h = h;
    return c.u;
}

// Barrier with LDS-only drain: global loads (private reg dests) stay in
// flight across it. "memory" clobbers fence compiler code motion both sides.
#define BAR() do {                                            \
        asm volatile("s_waitcnt lgkmcnt(0)" ::: "memory");    \
        __builtin_amdgcn_s_barrier();                         \
        asm volatile("" ::: "memory");                        \
    } while (0)

// ---------------- kernel 1: fused cast+norm+GEMM+masked-max ----------------
// grid: 1024 blocks (1-D, XCD-swizzled). 256 thr = 4 waves (2x2 of 64x64).
// Tile 128x128, BK=32, double-buffered bf16 LDS tiles written via ds_write.
// LDS layout: row stride 32 ushorts, chunk c (8 bf16) stored at slot c ^ s(row),
// s(r) = (r ^ (r>>2)) & 3  (bank-conflict-reduced b128 reads, proven r2-r10).
__global__ __launch_bounds__(256, 4)
void sim_fused(const float* __restrict__ e1, const float* __restrict__ e2,
               const int* __restrict__ m1g, const int* __restrict__ m2g,
               float* __restrict__ rowmax_p,   // [B][4][512]
               float* __restrict__ colmax_p)   // [B][4][512]
{
    // ---- XCD-batch-affinity decode: XCD (bid%8) owns 8 consecutive batches.
    const int bid = blockIdx.x;
    const int l   = ((bid & 7) << 7) | (bid >> 3);   // bijective, 1024 = 8*128
    const int b   = l >> 4;
    const int rt  = l & 3;
    const int ct  = (l >> 2) & 3;

    const int tid = threadIdx.x;
    const int lane = tid & 63;
    const int w    = tid >> 6;
    const int wm   = w >> 1;
    const int wn   = w & 1;
    const int q    = lane >> 4;
    const int ln   = lane & 15;
    const int nb   = ct * 128;                  // global col base

    __shared__ __align__(16) ushort sA[2][128 * 32];   // 2 x 8 KB
    __shared__ __align__(16) ushort sB[2][128 * 32];   // 2 x 8 KB
    // Epilogue aliases into parity-0 tile space (dead after the k-loop).
    float* spr   = reinterpret_cast<float*>(&sA[0][0]);     // [2][128] flat
    float* spc   = reinterpret_cast<float*>(&sA[0][512]);   // [2][128] flat
    int*   sm1   = reinterpret_cast<int*>(&sA[0][1024]);    // [128]
    int*   sm2   = reinterpret_cast<int*>(&sA[0][1280]);    // [128]
    float* sinv1 = reinterpret_cast<float*>(&sB[0][0]);     // [128]
    float* sinv2 = reinterpret_cast<float*>(&sB[0][256]);   // [128]

    // ---- staging mapping: thread (r = tid>>1, h = tid&1) covers row r,
    // k-local [h*16, h*16+16) each chunk, for both A and B tiles.
    const int r = tid >> 1;
    const int h = tid & 1;
    const int s = (r ^ (r >> 2)) & 3;
    const float* gA = e1 + ((size_t)(b * 512 + rt * 128 + r)) * 512 + h * 16;
    const float* gB = e2 + ((size_t)(b * 512 + nb + r)) * 512 + h * 16;
    // chunk c = 2h, 2h+1 -> slot c ^ s (ushort offsets)
    const int wo0 = r * 32 + (((2 * h)     ^ s) << 3);
    const int wo1 = r * 32 + (((2 * h + 1) ^ s) << 3);

    // ---- fragment read offsets (sln == s(frag_row), proven r2-r10)
    const int sln = (ln & 3) ^ ((ln >> 2) & 3);
    int aoff[4], boff[4];
    #pragma unroll
    for (int mt = 0; mt < 4; ++mt)
        aoff[mt] = (wm * 64 + mt * 16 + ln) * 32 + ((q ^ sln) << 3);
    #pragma unroll
    for (int nt = 0; nt < 4; ++nt)
        boff[nt] = (wn * 64 + nt * 16 + ln) * 32 + ((q ^ sln) << 3);

    float ssA = 0.f, ssB = 0.f;
    float4 ra[2][4], rb[2][4];     // 2-deep staging regs (one chunk each)

    auto LOADK = [&](int u, int kf) {     // kf = float offset of chunk
        const float4* pa = reinterpret_cast<const float4*>(gA + kf);
        const float4* pb = reinterpret_cast<const float4*>(gB + kf);
        ra[u][0] = pa[0]; ra[u][1] = pa[1]; ra[u][2] = pa[2]; ra[u][3] = pa[3];
        rb[u][0] = pb[0]; rb[u][1] = pb[1]; rb[u][2] = pb[2]; rb[u][3] = pb[3];
    };
    auto CVTWRITE = [&](int u, int pd) {
        // norm accumulation from the fp32 values (reference computes fp32 norms)
        #pragma unroll
        for (int i = 0; i < 4; ++i) {
            ssA += ra[u][i].x * ra[u][i].x + ra[u][i].y * ra[u][i].y
                 + ra[u][i].z * ra[u][i].z + ra[u][i].w * ra[u][i].w;
            ssB += rb[u][i].x * rb[u][i].x + rb[u][i].y * rb[u][i].y
                 + rb[u][i].z * rb[u][i].z + rb[u][i].w * rb[u][i].w;
        }
        uint4 v;
        v.x = packbf2_hw(ra[u][0].x, ra[u][0].y); v.y = packbf2_hw(ra[u][0].z, ra[u][0].w);
        v.z = packbf2_hw(ra[u][1].x, ra[u][1].y); v.w = packbf2_hw(ra[u][1].z, ra[u][1].w);
        *reinterpret_cast<uint4*>(&sA[pd][wo0]) = v;
        v.x = packbf2_hw(ra[u][2].x, ra[u][2].y); v.y = packbf2_hw(ra[u][2].z, ra[u][2].w);
        v.z = packbf2_hw(ra[u][3].x, ra[u][3].y); v.w = packbf2_hw(ra[u][3].z, ra[u][3].w);
        *reinterpret_cast<uint4*>(&sA[pd][wo1]) = v;
        v.x = packbf2_hw(rb[u][0].x, rb[u][0].y); v.y = packbf2_hw(rb[u][0].z, rb[u][0].w);
        v.z = packbf2_hw(rb[u][1].x, rb[u][1].y); v.w = packbf2_hw(rb[u][1].z, rb[u][1].w);
        *reinterpret_cast<uint4*>(&sB[pd][wo0]) = v;
        v.x = packbf2_hw(rb[u][2].x, rb[u][2].y); v.y = packbf2_hw(rb[u][2].z, rb[u][2].w);
        v.z = packbf2_hw(rb[u][3].x, rb[u][3].y); v.w = packbf2_hw(rb[u][3].z, rb[u][3].w);
        *reinterpret_cast<uint4*>(&sB[pd][wo1]) = v;
    };

    f32x4 acc[4][4];
    #pragma unroll
    for (int i = 0; i < 4; ++i)
        #pragma unroll
        for (int j = 0; j < 4; ++j)
            acc[i][j] = (f32x4){0.f, 0.f, 0.f, 0.f};

    // prologue: chunk 0 -> LDS buf0; chunk 1 -> regs buf1
    LOADK(0, 0);
    CVTWRITE(0, 0);
    LOADK(1, 32);
    BAR();

    // Per half-iter K (literal LDS/reg parity P):
    //   issue loads chunk K+2 -> regs[P] (earliest; ~1 iter before consume)
    //   ds_read frags from LDS[P]
    //   cvt+ds_write chunk K+1 (regs[P^1], loaded last iter) -> LDS[P^1]
    //   MFMA; lgkmcnt(0)-only barrier (globals stay in flight across it)
#define HALF_ITER(P, K)                                                    \
    do {                                                                   \
        if ((K) < 14) LOADK(P, ((K) + 2) * 32);                            \
        bf16x8 af[4], bfr[4];                                              \
        _Pragma("unroll")                                                  \
        for (int mt = 0; mt < 4; ++mt)                                     \
            af[mt] = *reinterpret_cast<const bf16x8*>(&sA[P][aoff[mt]]);   \
        _Pragma("unroll")                                                  \
        for (int nt = 0; nt < 4; ++nt)                                     \
            bfr[nt] = *reinterpret_cast<const bf16x8*>(&sB[P][boff[nt]]);  \
        if ((K) < 15) CVTWRITE((P) ^ 1, (P) ^ 1);                          \
        _Pragma("unroll")                                                  \
        for (int mt = 0; mt < 4; ++mt)                                     \
            _Pragma("unroll")                                              \
            for (int nt = 0; nt < 4; ++nt)                                 \
                acc[mt][nt] = __builtin_amdgcn_mfma_f32_16x16x32_bf16(     \
                    af[mt], bfr[nt], acc[mt][nt], 0, 0, 0);                \
        BAR();                                                             \
    } while (0)

    for (int kk = 0; kk < 8; ++kk) {
        HALF_ITER(0, 2 * kk);
        HALF_ITER(1, 2 * kk + 1);
    }
#undef HALF_ITER

    // ---- masks into dead parity-0 tile space; finish norms.
    // thread pair (2r, 2r+1) holds half-row sums each.
    if (tid < 128) sm1[tid] = m1g[b * 512 + rt * 128 + tid];
    else           sm2[tid - 128] = m2g[b * 512 + nb + (tid - 128)];
    ssA += __shfl_xor(ssA, 1);
    ssB += __shfl_xor(ssB, 1);
    if (h == 0) {
        sinv1[r] = 1.0f / fmaxf(sqrtf(ssA), 1e-8f);
        sinv2[r] = 1.0f / fmaxf(sqrtf(ssB), 1e-8f);
    }
    BAR();

    // ---- scale: sim = acc * inv_i * inv_j (C/D layout: col=ln, row=q*4+reg)
    float invj[4];
    f32x4 invi[4];
    #pragma unroll
    for (int nt = 0; nt < 4; ++nt)
        invj[nt] = sinv2[wn * 64 + nt * 16 + ln];
    #pragma unroll
    for (int mt = 0; mt < 4; ++mt)
        #pragma unroll
        for (int rg = 0; rg < 4; ++rg)
            invi[mt][rg] = sinv1[wm * 64 + mt * 16 + q * 4 + rg];
    #pragma unroll
    for (int mt = 0; mt < 4; ++mt)
        #pragma unroll
        for (int nt = 0; nt < 4; ++nt)
            acc[mt][nt] = acc[mt][nt] * (invi[mt] * invj[nt]);

    // ---- masked row maxes (over this block's 128 cols)
    #pragma unroll
    for (int mt = 0; mt < 4; ++mt) {
        #pragma unroll
        for (int rg = 0; rg < 4; ++rg) {
            float rm = NEGBIG;
            #pragma unroll
            for (int nt = 0; nt < 4; ++nt) {
                float v = sm2[wn * 64 + nt * 16 + ln] ? acc[mt][nt][rg] : NEGBIG;
                rm = fmaxf(rm, v);
            }
            rm = fmaxf(rm, __shfl_xor(rm, 1));
            rm = fmaxf(rm, __shfl_xor(rm, 2));
            rm = fmaxf(rm, __shfl_xor(rm, 4));
            rm = fmaxf(rm, __shfl_xor(rm, 8));
            if (ln == 0) spr[wn * 128 + wm * 64 + mt * 16 + q * 4 + rg] = rm;
        }
    }
    // ---- masked col maxes (over this block's 128 rows)
    #pragma unroll
    for (int nt = 0; nt < 4; ++nt) {
        float cm = NEGBIG;
        #pragma unroll
        for (int mt = 0; mt < 4; ++mt)
            #pragma unroll
            for (int rg = 0; rg < 4; ++rg) {
                float v = sm1[wm * 64 + mt * 16 + q * 4 + rg] ? acc[mt][nt][rg] : NEGBIG;
                cm = fmaxf(cm, v);
            }
        cm = fmaxf(cm, __shfl_xor(cm, 16));
        cm = fmaxf(cm, __shfl_xor(cm, 32));
        if (lane < 16) spc[wm * 128 + wn * 64 + nt * 16 + ln] = cm;
    }
    BAR();
    if (tid < 128) {
        rowmax_p[((size_t)b * 4 + ct) * 512 + rt * 128 + tid] =
            fmaxf(spr[tid], spr[128 + tid]);
        colmax_p[((size_t)b * 4 + rt) * 512 + nb + tid] =
            fmaxf(spc[tid], spc[128 + tid]);
    }
}

// ---------------- kernel 2: per-batch final reduction ----------------
__global__ __launch_bounds__(256)
void final_kernel(const int* __restrict__ m1g, const int* __restrict__ m2g,
                  const float* __restrict__ rowmax_p, const float* __restrict__ colmax_p,
                  float* __restrict__ out)
{
    const int b = blockIdx.x;
    const int tid = threadIdx.x;
    const int lane = tid & 63;
    const int w = tid >> 6;

    float sum = 0.f;
    float nn  = 0.f;
    for (int j = tid; j < 512; j += 256) {
        int mm1 = m1g[b * 512 + j];
        int mm2 = m2g[b * 512 + j];
        nn += (float)(mm1 + mm2);
        const float* rp = rowmax_p + (size_t)b * 2048 + j;
        float rm = fmaxf(fmaxf(rp[0], rp[512]), fmaxf(rp[1024], rp[1536]));
        if (mm1) sum += rm;
        const float* cp = colmax_p + (size_t)b * 2048 + j;
        float cm = fmaxf(fmaxf(cp[0], cp[512]), fmaxf(cp[1024], cp[1536]));
        if (mm2) sum += cm;
    }
    #pragma unroll
    for (int m = 32; m; m >>= 1) {
        sum += __shfl_xor(sum, m);
        nn  += __shfl_xor(nn, m);
    }
    __shared__ float ssum[4], snn[4];
    if (lane == 0) { ssum[w] = sum; snn[w] = nn; }
    __syncthreads();
    if (tid == 0) {
        float S = ssum[0] + ssum[1] + ssum[2] + ssum[3];
        float N = snn[0] + snn[1] + snn[2] + snn[3];
        out[b] = S / N;
    }
}

extern "C" void kernel_launch(void* const* d_in, const int* in_sizes, int n_in,
                              void* d_out, int out_size, void* d_ws, size_t ws_size,
                              hipStream_t stream) {
    const float* e1 = (const float*)d_in[0];
    const float* e2 = (const float*)d_in[1];
    const int*   m1 = (const int*)d_in[2];
    const int*   m2 = (const int*)d_in[3];
    float* out = (float*)d_out;

    float* ws = (float*)d_ws;             // 1 MB
    float* rowmax_p = ws;                 // 64*4*512
    float* colmax_p = ws + 131072;        // 64*4*512

    sim_fused<<<dim3(1024), 256, 0, stream>>>(e1, e2, m1, m2,
                                              rowmax_p, colmax_p);
    final_kernel<<<64, 256, 0, stream>>>(m1, m2, rowmax_p, colmax_p, out);
}

// Round 5
// 177.250 us; speedup vs baseline: 1.8906x; 1.8906x over previous
//
#include <hip/hip_runtime.h>
#include <hip/hip_bf16.h>

// Problem: B=64, S=512, D=512.
// out[b] = (sum_{valid i} max_{valid j} sim[i,j] + sum_{valid j} max_{valid i} sim[i,j]) / (n1+n2)
// sim = normalize(e1) @ normalize(e2)^T per batch.
//
// Round-12: r2 structure EXACTLY (75us @ 4 blocks/CU, VGPR 124) + the
// XCD-batch-affinity swizzle proven in r10/r3. No launch_bounds min-waves:
// r4 showed (256,4) forces a 64-VGPR tier -> 460MB of scratch spills ->
// 237us. The natural 124-VGPR allocation is already at the 4-waves/SIMD
// tier that the 4-blocks/CU grid needs.
// Fetch-bound model of r2: FETCH+WRITE = 198MB at achieved 2.65TB/s = 75us
// (the entire kernel time). Swizzle kills that traffic (r3: steady-state
// hbm_bytes ~1MB), so this round isolates [fetch-path fix] x [full occupancy].
// ws: 1 MB (partial maxes only).

typedef __attribute__((ext_vector_type(8))) short bf16x8;   // 8 bf16 in 4 VGPRs
typedef __attribute__((ext_vector_type(4))) float f32x4;

#define NEGBIG (-1e9f)

__device__ __forceinline__ unsigned packbf2_hw(float lo, float hi) {
    __hip_bfloat162 h = __float22bfloat162_rn(float2{lo, hi});
    union { __hip_bfloat162 h; unsigned u; } c; c.h = h;
    return c.u;
}

// Barrier with LDS-only drain: global loads (private reg dests) stay in
// flight across it. "memory" clobbers fence compiler code motion both sides.
#define BAR() do {                                            \
        asm volatile("s_waitcnt lgkmcnt(0)" ::: "memory");    \
        __builtin_amdgcn_s_barrier();                         \
        asm volatile("" ::: "memory");                        \
    } while (0)

// ---------------- kernel 1: fused cast+norm+GEMM+masked-max ----------------
// grid: 1024 blocks (1-D, XCD-swizzled). 256 thr = 4 waves (2x2 of 64x64).
// Tile 128x128, BK=32, double-buffered bf16 LDS tiles written via ds_write.
// LDS layout: row stride 32 ushorts, chunk c (8 bf16) stored at slot c ^ s(row),
// s(r) = (r ^ (r>>2)) & 3  (bank-conflict-reduced b128 reads, proven r2-r10).
__global__ __launch_bounds__(256)
void sim_fused(const float* __restrict__ e1, const float* __restrict__ e2,
               const int* __restrict__ m1g, const int* __restrict__ m2g,
               float* __restrict__ rowmax_p,   // [B][4][512]
               float* __restrict__ colmax_p)   // [B][4][512]
{
    // ---- XCD-batch-affinity decode: XCD (bid%8) owns 8 consecutive batches.
    const int bid = blockIdx.x;
    const int l   = ((bid & 7) << 7) | (bid >> 3);   // bijective, 1024 = 8*128
    const int b   = l >> 4;
    const int rt  = l & 3;
    const int ct  = (l >> 2) & 3;

    const int tid = threadIdx.x;
    const int lane = tid & 63;
    const int w    = tid >> 6;
    const int wm   = w >> 1;
    const int wn   = w & 1;
    const int q    = lane >> 4;
    const int ln   = lane & 15;
    const int nb   = ct * 128;                  // global col base

    __shared__ __align__(16) ushort sA[2][128 * 32];   // 2 x 8 KB
    __shared__ __align__(16) ushort sB[2][128 * 32];   // 2 x 8 KB
    // Epilogue aliases into parity-0 tile space (dead after the k-loop).
    float* spr   = reinterpret_cast<float*>(&sA[0][0]);     // [2][128] flat
    float* spc   = reinterpret_cast<float*>(&sA[0][512]);   // [2][128] flat
    int*   sm1   = reinterpret_cast<int*>(&sA[0][1024]);    // [128]
    int*   sm2   = reinterpret_cast<int*>(&sA[0][1280]);    // [128]
    float* sinv1 = reinterpret_cast<float*>(&sB[0][0]);     // [128]
    float* sinv2 = reinterpret_cast<float*>(&sB[0][256]);   // [128]

    // ---- staging mapping: thread (r = tid>>1, h = tid&1) covers row r,
    // k-local [h*16, h*16+16) each chunk, for both A and B tiles.
    const int r = tid >> 1;
    const int h = tid & 1;
    const int s = (r ^ (r >> 2)) & 3;
    const float* gA = e1 + ((size_t)(b * 512 + rt * 128 + r)) * 512 + h * 16;
    const float* gB = e2 + ((size_t)(b * 512 + nb + r)) * 512 + h * 16;
    // chunk c = 2h, 2h+1 -> slot c ^ s (ushort offsets)
    const int wo0 = r * 32 + (((2 * h)     ^ s) << 3);
    const int wo1 = r * 32 + (((2 * h + 1) ^ s) << 3);

    // ---- fragment read offsets (sln == s(frag_row), proven r2-r10)
    const int sln = (ln & 3) ^ ((ln >> 2) & 3);
    int aoff[4], boff[4];
    #pragma unroll
    for (int mt = 0; mt < 4; ++mt)
        aoff[mt] = (wm * 64 + mt * 16 + ln) * 32 + ((q ^ sln) << 3);
    #pragma unroll
    for (int nt = 0; nt < 4; ++nt)
        boff[nt] = (wn * 64 + nt * 16 + ln) * 32 + ((q ^ sln) << 3);

    float ssA = 0.f, ssB = 0.f;
    float4 ra[2][4], rb[2][4];     // 2-deep staging regs (one chunk each)

    auto LOADK = [&](int u, int kf) {     // kf = float offset of chunk
        const float4* pa = reinterpret_cast<const float4*>(gA + kf);
        const float4* pb = reinterpret_cast<const float4*>(gB + kf);
        ra[u][0] = pa[0]; ra[u][1] = pa[1]; ra[u][2] = pa[2]; ra[u][3] = pa[3];
        rb[u][0] = pb[0]; rb[u][1] = pb[1]; rb[u][2] = pb[2]; rb[u][3] = pb[3];
    };
    auto CVTWRITE = [&](int u, int pd) {
        // norm accumulation from the fp32 values (reference computes fp32 norms)
        #pragma unroll
        for (int i = 0; i < 4; ++i) {
            ssA += ra[u][i].x * ra[u][i].x + ra[u][i].y * ra[u][i].y
                 + ra[u][i].z * ra[u][i].z + ra[u][i].w * ra[u][i].w;
            ssB += rb[u][i].x * rb[u][i].x + rb[u][i].y * rb[u][i].y
                 + rb[u][i].z * rb[u][i].z + rb[u][i].w * rb[u][i].w;
        }
        uint4 v;
        v.x = packbf2_hw(ra[u][0].x, ra[u][0].y); v.y = packbf2_hw(ra[u][0].z, ra[u][0].w);
        v.z = packbf2_hw(ra[u][1].x, ra[u][1].y); v.w = packbf2_hw(ra[u][1].z, ra[u][1].w);
        *reinterpret_cast<uint4*>(&sA[pd][wo0]) = v;
        v.x = packbf2_hw(ra[u][2].x, ra[u][2].y); v.y = packbf2_hw(ra[u][2].z, ra[u][2].w);
        v.z = packbf2_hw(ra[u][3].x, ra[u][3].y); v.w = packbf2_hw(ra[u][3].z, ra[u][3].w);
        *reinterpret_cast<uint4*>(&sA[pd][wo1]) = v;
        v.x = packbf2_hw(rb[u][0].x, rb[u][0].y); v.y = packbf2_hw(rb[u][0].z, rb[u][0].w);
        v.z = packbf2_hw(rb[u][1].x, rb[u][1].y); v.w = packbf2_hw(rb[u][1].z, rb[u][1].w);
        *reinterpret_cast<uint4*>(&sB[pd][wo0]) = v;
        v.x = packbf2_hw(rb[u][2].x, rb[u][2].y); v.y = packbf2_hw(rb[u][2].z, rb[u][2].w);
        v.z = packbf2_hw(rb[u][3].x, rb[u][3].y); v.w = packbf2_hw(rb[u][3].z, rb[u][3].w);
        *reinterpret_cast<uint4*>(&sB[pd][wo1]) = v;
    };

    f32x4 acc[4][4];
    #pragma unroll
    for (int i = 0; i < 4; ++i)
        #pragma unroll
        for (int j = 0; j < 4; ++j)
            acc[i][j] = (f32x4){0.f, 0.f, 0.f, 0.f};

    // prologue: chunk 0 -> LDS buf0; chunk 1 -> regs buf1
    LOADK(0, 0);
    CVTWRITE(0, 0);
    LOADK(1, 32);
    BAR();

    // Per half-iter K (literal LDS/reg parity P):
    //   issue loads chunk K+2 -> regs[P] (earliest; ~1 iter before consume)
    //   ds_read frags from LDS[P]
    //   cvt+ds_write chunk K+1 (regs[P^1], loaded last iter) -> LDS[P^1]
    //   MFMA; lgkmcnt(0)-only barrier (globals stay in flight across it)
#define HALF_ITER(P, K)                                                    \
    do {                                                                   \
        if ((K) < 14) LOADK(P, ((K) + 2) * 32);                            \
        bf16x8 af[4], bfr[4];                                              \
        _Pragma("unroll")                                                  \
        for (int mt = 0; mt < 4; ++mt)                                     \
            af[mt] = *reinterpret_cast<const bf16x8*>(&sA[P][aoff[mt]]);   \
        _Pragma("unroll")                                                  \
        for (int nt = 0; nt < 4; ++nt)                                     \
            bfr[nt] = *reinterpret_cast<const bf16x8*>(&sB[P][boff[nt]]);  \
        if ((K) < 15) CVTWRITE((P) ^ 1, (P) ^ 1);                          \
        _Pragma("unroll")                                                  \
        for (int mt = 0; mt < 4; ++mt)                                     \
            _Pragma("unroll")                                              \
            for (int nt = 0; nt < 4; ++nt)                                 \
                acc[mt][nt] = __builtin_amdgcn_mfma_f32_16x16x32_bf16(     \
                    af[mt], bfr[nt], acc[mt][nt], 0, 0, 0);                \
        BAR();                                                             \
    } while (0)

    for (int kk = 0; kk < 8; ++kk) {
        HALF_ITER(0, 2 * kk);
        HALF_ITER(1, 2 * kk + 1);
    }
#undef HALF_ITER

    // ---- masks into dead parity-0 tile space; finish norms.
    // thread pair (2r, 2r+1) holds half-row sums each.
    if (tid < 128) sm1[tid] = m1g[b * 512 + rt * 128 + tid];
    else           sm2[tid - 128] = m2g[b * 512 + nb + (tid - 128)];
    ssA += __shfl_xor(ssA, 1);
    ssB += __shfl_xor(ssB, 1);
    if (h == 0) {
        sinv1[r] = 1.0f / fmaxf(sqrtf(ssA), 1e-8f);
        sinv2[r] = 1.0f / fmaxf(sqrtf(ssB), 1e-8f);
    }
    BAR();

    // ---- scale: sim = acc * inv_i * inv_j (C/D layout: col=ln, row=q*4+reg)
    float invj[4];
    f32x4 invi[4];
    #pragma unroll
    for (int nt = 0; nt < 4; ++nt)
        invj[nt] = sinv2[wn * 64 + nt * 16 + ln];
    #pragma unroll
    for (int mt = 0; mt < 4; ++mt)
        #pragma unroll
        for (int rg = 0; rg < 4; ++rg)
            invi[mt][rg] = sinv1[wm * 64 + mt * 16 + q * 4 + rg];
    #pragma unroll
    for (int mt = 0; mt < 4; ++mt)
        #pragma unroll
        for (int nt = 0; nt < 4; ++nt)
            acc[mt][nt] = acc[mt][nt] * (invi[mt] * invj[nt]);

    // ---- masked row maxes (over this block's 128 cols)
    #pragma unroll
    for (int mt = 0; mt < 4; ++mt) {
        #pragma unroll
        for (int rg = 0; rg < 4; ++rg) {
            float rm = NEGBIG;
            #pragma unroll
            for (int nt = 0; nt < 4; ++nt) {
                float v = sm2[wn * 64 + nt * 16 + ln] ? acc[mt][nt][rg] : NEGBIG;
                rm = fmaxf(rm, v);
            }
            rm = fmaxf(rm, __shfl_xor(rm, 1));
            rm = fmaxf(rm, __shfl_xor(rm, 2));
            rm = fmaxf(rm, __shfl_xor(rm, 4));
            rm = fmaxf(rm, __shfl_xor(rm, 8));
            if (ln == 0) spr[wn * 128 + wm * 64 + mt * 16 + q * 4 + rg] = rm;
        }
    }
    // ---- masked col maxes (over this block's 128 rows)
    #pragma unroll
    for (int nt = 0; nt < 4; ++nt) {
        float cm = NEGBIG;
        #pragma unroll
        for (int mt = 0; mt < 4; ++mt)
            #pragma unroll
            for (int rg = 0; rg < 4; ++rg) {
                float v = sm1[wm * 64 + mt * 16 + q * 4 + rg] ? acc[mt][nt][rg] : NEGBIG;
                cm = fmaxf(cm, v);
            }
        cm = fmaxf(cm, __shfl_xor(cm, 16));
        cm = fmaxf(cm, __shfl_xor(cm, 32));
        if (lane < 16) spc[wm * 128 + wn * 64 + nt * 16 + ln] = cm;
    }
    BAR();
    if (tid < 128) {
        rowmax_p[((size_t)b * 4 + ct) * 512 + rt * 128 + tid] =
            fmaxf(spr[tid], spr[128 + tid]);
        colmax_p[((size_t)b * 4 + rt) * 512 + nb + tid] =
            fmaxf(spc[tid], spc[128 + tid]);
    }
}

// ---------------- kernel 2: per-batch final reduction ----------------
__global__ __launch_bounds__(256)
void final_kernel(const int* __restrict__ m1g, const int* __restrict__ m2g,
                  const float* __restrict__ rowmax_p, const float* __restrict__ colmax_p,
                  float* __restrict__ out)
{
    const int b = blockIdx.x;
    const int tid = threadIdx.x;
    const int lane = tid & 63;
    const int w = tid >> 6;

    float sum = 0.f;
    float nn  = 0.f;
    for (int j = tid; j < 512; j += 256) {
        int mm1 = m1g[b * 512 + j];
        int mm2 = m2g[b * 512 + j];
        nn += (float)(mm1 + mm2);
        const float* rp = rowmax_p + (size_t)b * 2048 + j;
        float rm = fmaxf(fmaxf(rp[0], rp[512]), fmaxf(rp[1024], rp[1536]));
        if (mm1) sum += rm;
        const float* cp = colmax_p + (size_t)b * 2048 + j;
        float cm = fmaxf(fmaxf(cp[0], cp[512]), fmaxf(cp[1024], cp[1536]));
        if (mm2) sum += cm;
    }
    #pragma unroll
    for (int m = 32; m; m >>= 1) {
        sum += __shfl_xor(sum, m);
        nn  += __shfl_xor(nn, m);
    }
    __shared__ float ssum[4], snn[4];
    if (lane == 0) { ssum[w] = sum; snn[w] = nn; }
    __syncthreads();
    if (tid == 0) {
        float S = ssum[0] + ssum[1] + ssum[2] + ssum[3];
        float N = snn[0] + snn[1] + snn[2] + snn[3];
        out[b] = S / N;
    }
}

extern "C" void kernel_launch(void* const* d_in, const int* in_sizes, int n_in,
                              void* d_out, int out_size, void* d_ws, size_t ws_size,
                              hipStream_t stream) {
    const float* e1 = (const float*)d_in[0];
    const float* e2 = (const float*)d_in[1];
    const int*   m1 = (const int*)d_in[2];
    const int*   m2 = (const int*)d_in[3];
    float* out = (float*)d_out;

    float* ws = (float*)d_ws;             // 1 MB
    float* rowmax_p = ws;                 // 64*4*512
    float* colmax_p = ws + 131072;        // 64*4*512

    sim_fused<<<dim3(1024), 256, 0, stream>>>(e1, e2, m1, m2,
                                              rowmax_p, colmax_p);
    final_kernel<<<64, 256, 0, stream>>>(m1, m2, rowmax_p, colmax_p, out);
}